// Round 2
// baseline (15556.383 us; speedup 1.0000x reference)
//
#include <hip/hip_runtime.h>
#include <math.h>

// ============================================================================
// S2CNN regression — round 1: fix HSA abort from round 0.
//   * Workspace footprint 317MB -> ~85MB (chunked transitions through an 8MB
//     bounce buffer; l-grouped kh through a 12MB buffer) + ws_size guard.
//   * k_dft2 LDS 64KB -> 33KB: K-entry twiddle table + strength-reduced
//     exponents (K power of two: r = (r+s) & (K-1)).
// Pipeline identical in math to round 0 (verified against reference algebra).
// ============================================================================

#define PI_D 3.14159265358979323846

__host__ __device__ __forceinline__ int offl_(int l) { return l*(2*l-1)*(2*l+1)/3; }
static inline int Sof(int b) { return b*(4*b*b-1)/3; }           // sum_{l<b}(2l+1)^2
static inline unsigned cdiv(long a, long b) { return (unsigned)((a + b - 1) / b); }

__device__ __constant__ float COS6[6] = {1.f, .5f, -.5f, -1.f, -.5f, .5f};
__device__ __constant__ float SIN6[6] = {0.f, 0.8660254037844386f, 0.8660254037844386f,
                                         0.f, -0.8660254037844386f, -0.8660254037844386f};

// ---------------- table generation ----------------
__global__ void k_lf(double* lf) {
  int n = threadIdx.x;                 // 0..63
  double s = 0.0;
  for (int j = 2; j <= n; ++j) s += log((double)j);
  lf[n] = s;
}

__global__ void k_qw(int b, float* out) {
  int k = threadIdx.x, K = 2*b;
  if (k >= K) return;
  double beta = PI_D*(2*k+1)/(4.0*b);
  double s = 0.0;
  for (int j = 0; j < b; ++j)
    s += sin(PI_D*(double)(2*k+1)*(double)(2*j+1)/(4.0*b)) / (double)(2*j+1);
  out[k] = (float)((2.0/b)*sin(beta)*s);
}

// d^l_{m,n}(beta) = <m| e^{-i beta Jy} |n>, explicit Jacobi sum, fp64.
// Layout: out[K*offl(l) + k*(2l+1)^2 + (m+l)*(2l+1) + (n+l)]
__global__ void k_wigner(int L, int K, double beta0, const double* __restrict__ lf,
                         float* __restrict__ out) {
  int l = blockIdx.y;
  int d = 2*l+1, dd = d*d;
  long total = (long)K*dd;
  long idx = (long)blockIdx.x*blockDim.x + threadIdx.x;
  if (idx >= total) return;
  int k = (int)(idx / dd), r = (int)(idx % dd);
  int mi = r/d, ni = r - mi*d, m = mi-l, n = ni-l;
  double beta = (K == 1) ? beta0 : PI_D*(double)(2*k+1)/(2.0*K);
  double cb = cos(0.5*beta), sb = sin(0.5*beta);
  double lc = log(cb), ls = log(sb);
  double pref = 0.5*(lf[l+m]+lf[l-m]+lf[l+n]+lf[l-n]);
  int smin = (n-m > 0) ? (n-m) : 0;
  int smax = (l+n < l-m) ? (l+n) : (l-m);
  double sum = 0.0;
  for (int s = smin; s <= smax; ++s) {
    double t = pref - lf[l+n-s] - lf[s] - lf[m-n+s] - lf[l-m-s]
             + (double)(2*l+n-m-2*s)*lc + (double)(m-n+2*s)*ls;
    double e = exp(t);
    sum += ((m-n+s) & 1) ? -e : e;
  }
  out[(long)K*offl_(l) + idx] = (float)sum;
}

// ---------------- DFT kernels ----------------
// 1-D forward DFT (last axis), centered: X[i] = sum_j x[j] e^{-2pi i j(i-K/2)/K}
__global__ void k_dft1(const float* __restrict__ in, float2* __restrict__ out, int K) {
  __shared__ float row[64];
  int tid = threadIdx.x;
  long base = (long)blockIdx.x * K;
  row[tid] = in[base + tid];
  __syncthreads();
  int i = tid;
  float2 acc = make_float2(0.f, 0.f);
  float c0 = 6.28318530717958647692f / K;
  for (int j = 0; j < K; ++j) {
    int r = (j * ((K + K/2 - i) & (K-1))) & (K-1);   // (-(j*(i-K/2))) mod K
    float s, c; sincosf(c0 * (float)r, &s, &c);
    acc.x += row[j]*c; acc.y += row[j]*s;
  }
  out[base + i] = acc;
}

// 2-D DFT over a KxK tile per block (K power of two).
// fwd (inv=0): real in, complex centered out. inv (inv=1): complex centered in,
// real out (opt ReLU). No scaling either way (ifft2*K^2 cancels).
// LDS: K twiddles (e^{+2pi i r/K}) + K*K tile = 8K + 8K^2 bytes (33KB @ K=64).
__global__ void k_dft2(const float* __restrict__ inR, const float2* __restrict__ inC,
                       float2* __restrict__ outC, float* __restrict__ outR,
                       int K, int inv, int relu) {
  extern __shared__ float sm[];
  float2* Wt = (float2*)sm;           // K twiddles
  float2* T  = ((float2*)sm) + K;     // K*K tile
  const int bs = blockDim.x, tid = threadIdx.x;
  const int Km1 = K - 1;
  const long base = (long)blockIdx.x * K * K;
  const float c0 = 6.28318530717958647692f / K;
  for (int r = tid; r < K; r += bs) {
    float s, c; sincosf(c0 * (float)r, &s, &c);
    Wt[r] = make_float2(c, s);
  }
  for (int idx = tid; idx < K*K; idx += bs)
    T[idx] = inv ? inC[base + idx] : make_float2(inR[base + idx], 0.f);
  __syncthreads();
  // pass 1: transform last axis (register-buffered, then write back)
  float2 racc[16];
  int cnt = 0;
  for (int idx = tid; idx < K*K; idx += bs, ++cnt) {
    int a = idx / K, i = idx - a*K;
    int s = inv ? i : ((K + K/2 - i) & Km1);
    int r = inv ? ((i & 1) ? K/2 : 0) : 0;
    float2 acc = make_float2(0.f, 0.f);
    const float2* Trow = T + a*K;
    for (int j = 0; j < K; ++j) {
      float2 tv = Trow[j], w = Wt[r];
      acc.x += tv.x*w.x - tv.y*w.y;
      acc.y += tv.x*w.y + tv.y*w.x;
      r = (r + s) & Km1;
    }
    racc[cnt] = acc;
  }
  __syncthreads();
  cnt = 0;
  for (int idx = tid; idx < K*K; idx += bs, ++cnt) T[idx] = racc[cnt];
  __syncthreads();
  // pass 2: transform axis -2
  for (int idx = tid; idx < K*K; idx += bs) {
    int ia = idx / K, ig = idx - ia*K;
    int s = inv ? ia : ((K + K/2 - ia) & Km1);
    int r = inv ? ((ia & 1) ? K/2 : 0) : 0;
    float2 acc = make_float2(0.f, 0.f);
    for (int j = 0; j < K; ++j) {
      float2 tv = T[j*K + ig], w = Wt[r];
      acc.x += tv.x*w.x - tv.y*w.y;
      acc.y += tv.x*w.y + tv.y*w.x;
      r = (r + s) & Km1;
    }
    if (!inv) outC[base + idx] = acc;
    else {
      float v = acc.x;
      if (relu) v = fmaxf(v, 0.f);
      outR[base + idx] = v;
    }
  }
}

// ---------------- Wigner analysis (beta-sum) ----------------
// xh[bc, off(l)+mi*d+ni] = sum_k qw[k]*d^l[k,mi,ni]*X[bc,k,K/2+m,K/2+n]
__global__ void k_analysis(const float2* __restrict__ X, const float* __restrict__ wig,
                           const float* __restrict__ qw, float2* __restrict__ xh,
                           int BC, int K, int Sstride) {
  int l = blockIdx.y, d = 2*l+1, dd = d*d;
  long total = (long)BC*dd;
  long idx = (long)blockIdx.x*blockDim.x + threadIdx.x;
  if (idx >= total) return;
  int bc = (int)(idx / dd), r = (int)(idx % dd);
  int mi = r/d, ni = r - mi*d, m = mi-l, n = ni-l;
  const float* wl = wig + (long)K*offl_(l);
  const float2* Xp = X + (long)bc*K*K*K + (long)(K/2+m)*K + (K/2+n);
  float2 acc = make_float2(0.f, 0.f);
  for (int k = 0; k < K; ++k) {
    float w = qw[k] * wl[(long)k*dd + r];
    float2 xv = Xp[(long)k*K*K];
    acc.x += w*xv.x; acc.y += w*xv.y;
  }
  xh[(long)bc*Sstride + offl_(l) + r] = acc;
}

// s2 variant: 1-D windows, n=0 column. stride 1024, offset l^2.
__global__ void k_analysis_s2(const float2* __restrict__ X, const float* __restrict__ wig,
                              const float* __restrict__ qw, float2* __restrict__ xh,
                              int BC, int K) {
  int l = blockIdx.y, d = 2*l+1, dd = d*d;
  long total = (long)BC*d;
  long idx = (long)blockIdx.x*blockDim.x + threadIdx.x;
  if (idx >= total) return;
  int bc = (int)(idx / d), mi = (int)(idx % d), m = mi - l;
  const float* wl = wig + (long)K*offl_(l);
  float2 acc = make_float2(0.f, 0.f);
  for (int k = 0; k < K; ++k) {
    float w = qw[k] * wl[(long)k*dd + mi*d + l];
    float2 xv = X[((long)bc*K + k)*K + (K/2+m)];
    acc.x += w*xv.x; acc.y += w*xv.y;
  }
  xh[(long)bc*1024 + l*l + mi] = acc;
}

// ---------------- spectral kernels from weights (l-grouped) ----------------
// kh[cf, Sg-packed] = d0 * sum_{a,g} w[cf,a,g] e^{i(m*alpha_a + n*gamma_g)}
__global__ void k_kh(const float* __restrict__ w, const float* __restrict__ d0,
                     float2* __restrict__ kh, int C, int F, int l0, int koff0, int Sg) {
  int l = blockIdx.y + l0, d = 2*l+1, dd = d*d;
  long total = (long)C*F*dd;
  long idx = (long)blockIdx.x*blockDim.x + threadIdx.x;
  if (idx >= total) return;
  int cf = (int)(idx / dd), r = (int)(idx % dd);
  int mi = r/d, ni = r - mi*d, m = mi-l, n = ni-l;
  const float* wp = w + (long)cf*36;
  float re = 0.f, im = 0.f;
  for (int a = 0; a < 6; ++a) {
    int pa = ((m*a) % 6 + 6) % 6;
    for (int g = 0; g < 6; ++g) {
      int p = (pa + ((n*g) % 6 + 6) % 6) % 6;
      float wv = wp[a*6 + g];
      re += wv*COS6[p]; im += wv*SIN6[p];
    }
  }
  float dv = d0[offl_(l) + r];
  kh[(long)cf*Sg + (offl_(l) - koff0) + r] = make_float2(re*dv, im*dv);
}

// s2: kh[cf, l^2+mi] = d^l_{m,0}(b0) * sum_j w[cf,j] e^{-i m alpha_j}
__global__ void k_kh_s2(const float* __restrict__ w, const float* __restrict__ d0,
                        float2* __restrict__ kh, int C, int F) {
  int l = blockIdx.y, d = 2*l+1;
  long total = (long)C*F*d;
  long idx = (long)blockIdx.x*blockDim.x + threadIdx.x;
  if (idx >= total) return;
  int cf = (int)(idx / d), mi = (int)(idx % d), m = mi - l;
  const float* wp = w + (long)cf*6;
  float re = 0.f, im = 0.f;
  for (int j = 0; j < 6; ++j) {
    int p = ((-m*j) % 6 + 6) % 6;
    re += wp[j]*COS6[p]; im += wp[j]*SIN6[p];
  }
  float dv = d0[offl_(l) + mi*d + l];
  kh[(long)cf*1024 + l*l + mi] = make_float2(re*dv, im*dv);
}

// s2 rank-1: yl[b,f,m,n] = sum_c xh[b,c,m]*kh[c,f,n]
__global__ void k_rank1(const float2* __restrict__ xh, const float2* __restrict__ kh,
                        float2* __restrict__ yl, int B, int C, int F, int Sout) {
  int l = blockIdx.y, d = 2*l+1, dd = d*d;
  long total = (long)B*F*dd;
  long idx = (long)blockIdx.x*blockDim.x + threadIdx.x;
  if (idx >= total) return;
  int bf = (int)(idx / dd), r = (int)(idx % dd);
  int b = bf / F, f = bf - b*F;
  int mi = r/d, ni = r - mi*d;
  float2 acc = make_float2(0.f, 0.f);
  for (int c = 0; c < C; ++c) {
    float2 xv = xh[((long)b*C + c)*1024 + l*l + mi];
    float2 kv = kh[((long)c*F + f)*1024 + l*l + ni];
    acc.x += xv.x*kv.x - xv.y*kv.y;
    acc.y += xv.x*kv.y + xv.y*kv.x;
  }
  yl[(long)bf*Sout + offl_(l) + r] = acc;
}

// per-degree complex matmul (kh l-grouped): yl (+)= xh @ kh
__global__ void k_matmul(const float2* __restrict__ xh, int xhS,
                         const float2* __restrict__ kh, int khS, int koff0, int l0,
                         float2* __restrict__ yl, int ylS,
                         int B, int C, int F, int accf) {
  int l = blockIdx.y + l0, d = 2*l+1, dd = d*d;
  long total = (long)B*F*dd;
  long idx = (long)blockIdx.x*blockDim.x + threadIdx.x;
  if (idx >= total) return;
  int bf = (int)(idx / dd), r = (int)(idx % dd);
  int b = bf / F, f = bf - b*F;
  int mi = r/d, ni = r - mi*d;
  int ol = offl_(l), olk = ol - koff0;
  float2 acc = make_float2(0.f, 0.f);
  for (int c = 0; c < C; ++c) {
    const float2* xr = xh + ((long)b*C + c)*xhS + ol + (long)mi*d;
    const float2* kr = kh + ((long)c*F + f)*khS + olk + ni;
    for (int p = 0; p < d; ++p) {
      float2 xv = xr[p], kv = kr[(long)p*d];
      acc.x += xv.x*kv.x - xv.y*kv.y;
      acc.y += xv.x*kv.y + xv.y*kv.x;
    }
  }
  float2* o = yl + (long)bf*ylS + ol + r;
  if (accf) { float2 v = *o; v.x += acc.x; v.y += acc.y; *o = v; }
  else *o = acc;
}

// synthesis gather: g[bf,k,i,j] = sum_{l>=lmin} d^l[k]*yl[bf,l]
__global__ void k_buildg(const float2* __restrict__ yl, int ylS,
                         const float* __restrict__ wig, float2* __restrict__ g,
                         int BF, int K, int L) {
  long tot = (long)BF*K*K*K;
  long idx = (long)blockIdx.x*blockDim.x + threadIdx.x;
  if (idx >= tot) return;
  int j = (int)(idx % K); long t = idx / K;
  int i = (int)(t % K); t /= K;
  int k = (int)(t % K); int bf = (int)(t / K);
  int m = i - K/2, n = j - K/2;
  int am = m < 0 ? -m : m, an = n < 0 ? -n : n;
  int lmin = am > an ? am : an;
  float2 acc = make_float2(0.f, 0.f);
  for (int l = lmin; l < L; ++l) {
    int d = 2*l+1;
    int r = (m+l)*d + (n+l);
    float wv = wig[(long)K*offl_(l) + (long)k*d*d + r];
    float2 yv = yl[(long)bf*ylS + offl_(l) + r];
    acc.x += wv*yv.x; acc.y += wv*yv.y;
  }
  g[idx] = acc;
}

// integrate over SO(3) at b=2 + linear head
__global__ void k_final(const float* __restrict__ h, const float* __restrict__ qw,
                        const float* __restrict__ lw, const float* __restrict__ lb,
                        float* __restrict__ out) {
  int b = blockIdx.x, f = threadIdx.x;   // 4 blocks x 256 threads
  const float* hp = h + ((long)b*256 + f)*64;
  float s = 0.f;
  for (int k = 0; k < 4; ++k) {
    float q = qw[k];
    for (int ag = 0; ag < 16; ++ag) s += hp[k*16 + ag]*q;
  }
  s = s * 0.0625f * lw[f];
  __shared__ float red[256];
  red[f] = s; __syncthreads();
  for (int st = 128; st > 0; st >>= 1) {
    if (f < st) red[f] += red[f + st];
    __syncthreads();
  }
  if (f == 0) out[b] = red[0] + lb[0];
}

// ============================================================================
extern "C" void kernel_launch(void* const* d_in, const int* in_sizes, int n_in,
                              void* d_out, int out_size, void* d_ws, size_t ws_size,
                              hipStream_t stream) {
  (void)in_sizes; (void)n_in;
  const float* x   = (const float*)d_in[0];
  const float* ks2 = (const float*)d_in[1];
  const float* lw  = (const float*)d_in[14];
  const float* lb  = (const float*)d_in[15];
  float* out = (float*)d_out;

  const int bl[5] = {32, 16, 8, 4, 2};
  char* ws = (char*)d_ws;
  size_t off = 0;
  auto alloc = [&](size_t nbytes) -> char* {
    char* p = ws + off;
    off += (nbytes + 255) & ~(size_t)255;
    return p;
  };

  double* lf = (double*)alloc(64*sizeof(double));
  float* qwT[5]; float* wigT[5]; float* d0T[4];
  for (int i = 0; i < 5; ++i) qwT[i]  = (float*)alloc((size_t)2*bl[i]*4);
  for (int i = 0; i < 5; ++i) wigT[i] = (float*)alloc((size_t)2*bl[i]*Sof(bl[i])*4);
  for (int i = 0; i < 4; ++i) d0T[i]  = (float*)alloc((size_t)Sof(bl[i])*4);

  const size_t GCAP = 8u<<20, RCAP = 4u<<20, KHCAP = 12u<<20;
  float2* G   = (float2*)alloc(GCAP);                 // complex bounce buffer
  float*  Rc  = (float*)alloc(RCAP);                  // real bounce buffer
  float2* KH  = (float2*)alloc(KHCAP);                // l-grouped spectral kernels
  float2* XH  = (float2*)alloc((size_t)64*43680*8);   // packed xh, block input
  float2* YL  = (float2*)alloc((size_t)64*43680*8);   // packed yl
  float2* XHA = (float2*)alloc((size_t)64*5456*8);    // packed xh of ha
  float2* XS2 = (float2*)alloc((size_t)1024*64*8);
  float2* XHS = (float2*)alloc((size_t)16*1024*8);
  float2* KHS = (float2*)alloc((size_t)64*1024*8);
  float*  OUTS= (float*)alloc((size_t)1024*64*4);     // final block output signals

  if (off > ws_size) {   // workspace too small: fail loud-but-clean (no OOB)
    hipMemsetAsync(d_out, 0, (size_t)out_size*sizeof(float), stream);
    return;
  }

  // ---- tables ----
  k_lf<<<1, 64, 0, stream>>>(lf);
  for (int i = 0; i < 5; ++i) k_qw<<<1, 64, 0, stream>>>(bl[i], qwT[i]);
  for (int i = 0; i < 5; ++i) {
    int L = bl[i], K = 2*L, md = 2*L-1;
    k_wigner<<<dim3(cdiv((long)K*md*md, 256), L), 256, 0, stream>>>(L, K, 0.0, lf, wigT[i]);
  }
  const double b0s[4] = {PI_D/16, PI_D/8, PI_D/4, PI_D/2};
  for (int i = 0; i < 4; ++i) {
    int L = bl[i], md = 2*L-1;
    k_wigner<<<dim3(cdiv((long)md*md, 256), L), 256, 0, stream>>>(L, 1, b0s[i], lf, d0T[i]);
  }

  // transition: yl --buildg--> g --idft+relu--> real --fdft--> X --analysis--> xh
  auto transition = [&](const float2* yl, int ylS, int Lsyn, const float* wsyn,
                        int K, const float* wana, const float* qana,
                        int Lana, int Sana, float2* xh_out, int nsig) {
    long per = (long)K*K*K;
    long c1 = (long)(GCAP/8)/per, c2 = (long)(RCAP/4)/per;
    int CH = (int)(c1 < c2 ? c1 : c2);
    if (CH > nsig) CH = nsig;
    if (CH < 1) CH = 1;
    int bsK = (K*K >= 256) ? 256 : 64;
    size_t sh = 8u*(size_t)K + 8u*(size_t)K*K;
    int dd = (2*Lana-1)*(2*Lana-1);
    for (int s0 = 0; s0 < nsig; s0 += CH) {
      int ch = (nsig - s0 < CH) ? (nsig - s0) : CH;
      k_buildg<<<cdiv((long)ch*per, 256), 256, 0, stream>>>(
          yl + (long)s0*ylS, ylS, wsyn, G, ch, K, Lsyn);
      k_dft2<<<ch*K, bsK, sh, stream>>>(nullptr, G, nullptr, Rc, K, 1, 1);
      k_dft2<<<ch*K, bsK, sh, stream>>>(Rc, nullptr, G, nullptr, K, 0, 0);
      k_analysis<<<dim3(cdiv((long)ch*dd, 256), Lana), 256, 0, stream>>>(
          G, wana, qana, xh_out + (long)s0*Sana, ch, K, Sana);
    }
  };

  // kh built in degree groups through KH, matmul'd immediately
  auto conv_matmul = [&](const float* w, const float* d0, const float2* xh, int xhS,
                         float2* yl, int ylS, int B, int C, int F, int L, int accf) {
    int l0 = 0;
    while (l0 < L) {
      int l1 = l0; long sg = 0;
      while (l1 < L) {
        long dd = (long)(2*l1+1)*(2*l1+1);
        if (l1 > l0 && (size_t)C*F*(size_t)(sg+dd)*8 > KHCAP) break;
        sg += dd; ++l1;
      }
      int koff0 = offl_(l0);
      int ddmax = (2*l1-1)*(2*l1-1);
      k_kh<<<dim3(cdiv((long)C*F*ddmax, 256), l1-l0), 256, 0, stream>>>(
          w, d0, KH, C, F, l0, koff0, (int)sg);
      k_matmul<<<dim3(cdiv((long)B*F*ddmax, 256), l1-l0), 256, 0, stream>>>(
          xh, xhS, KH, (int)sg, koff0, l0, yl, ylS, B, C, F, accf);
      l0 = l1;
    }
  };

  // ---- s2 conv (b=32) -> transition -> XH for block 1 ----
  k_dft1<<<1024, 64, 0, stream>>>(x, XS2, 64);
  k_analysis_s2<<<dim3(cdiv(16L*63, 256), 32), 256, 0, stream>>>(XS2, wigT[0], qwT[0], XHS, 16, 64);
  k_kh_s2<<<dim3(cdiv(64L*63, 256), 32), 256, 0, stream>>>(ks2, d0T[0], KHS, 4, 16);
  k_rank1<<<dim3(cdiv(64L*3969, 256), 32), 256, 0, stream>>>(XHS, KHS, YL, 4, 4, 16, 43680);
  transition(YL, 43680, 32, wigT[0], 64, wigT[0], qwT[0], 32, 43680, XH, 64);

  // ---- residual blocks ----
  const float* wa_[4] = {(const float*)d_in[2], (const float*)d_in[5], (const float*)d_in[8],  (const float*)d_in[11]};
  const float* wb_[4] = {(const float*)d_in[3], (const float*)d_in[6], (const float*)d_in[9],  (const float*)d_in[12]};
  const float* wsn[4] = {(const float*)d_in[4], (const float*)d_in[7], (const float*)d_in[10], (const float*)d_in[13]};
  const int Cs[4] = {16, 32, 64, 128}, Fs[4] = {32, 64, 128, 256};

  for (int blk = 0; blk < 4; ++blk) {
    const int bw = bl[blk], C = Cs[blk], F = Fs[blk], B = 4;
    const int L = bw, Lh = bw/2, K = 2*bw, Kh = bw;
    const int Sa = Sof(L), Sh = Sof(Lh);

    // a-conv: yl_a = xh_in @ kh_a     (full L levels)
    conv_matmul(wa_[blk], d0T[blk], XH, Sa, YL, Sa, B, C, C, L, 0);
    // ha transition: yl_a -> relu signal -> xh_a (Lh levels, same b_in grid)
    transition(YL, Sa, L, wigT[blk], K, wigT[blk], qwT[blk], Lh, Sh, XHA, B*C);
    // b-conv: yl = xh_a @ kh_b
    conv_matmul(wb_[blk], d0T[blk], XHA, Sh, YL, Sh, B, C, F, Lh, 0);
    // shortcut: yl += xh_in(prefix) @ kh_s
    conv_matmul(wsn[blk], d0T[blk], XH, Sa, YL, Sh, B, C, F, Lh, 1);

    if (blk < 3) {
      // output transition: synthesize at b=Lh on Kh grid, analyze for next block
      transition(YL, Sh, Lh, wigT[blk+1], Kh, wigT[blk+1], qwT[blk+1], Lh, Sh, XH, B*F);
    } else {
      // final output: synthesize + idft(+relu) to OUTS (b=2, K=4)
      long per = (long)Kh*Kh*Kh;
      int nsig = B*F;
      int bsK = (Kh*Kh >= 256) ? 256 : 64;
      size_t sh = 8u*(size_t)Kh + 8u*(size_t)Kh*Kh;
      int CH = (int)((long)(GCAP/8)/per); if (CH > nsig) CH = nsig;
      for (int s0 = 0; s0 < nsig; s0 += CH) {
        int ch = (nsig - s0 < CH) ? (nsig - s0) : CH;
        k_buildg<<<cdiv((long)ch*per, 256), 256, 0, stream>>>(
            YL + (long)s0*Sh, Sh, wigT[4], G, ch, Kh, Lh);
        k_dft2<<<ch*Kh, bsK, sh, stream>>>(nullptr, G, nullptr, OUTS + (long)s0*per, Kh, 1, 1);
      }
    }
  }

  // ---- integrate (b=2) + linear head ----
  k_final<<<4, 256, 0, stream>>>(OUTS, qwT[4], lw, lb, out);
}

// Round 3
// 11343.152 us; speedup vs baseline: 1.3714x; 1.3714x over previous
//
#include <hip/hip_runtime.h>
#include <math.h>

// ============================================================================
// S2CNN regression — round 2.
//  R1 passed at 15.56ms. Dominant cost: naive O(K^2)-per-point DFTs (~78 GF
//  fp32 at ~16 TF effective) + separate buildg/relu round-trips.
//  This round:
//   * Radix-2 Stockham FFT in LDS (13x flop cut at K=64), shifts folded into
//     index XOR K/2, standard-order spectra everywhere downstream.
//   * Fused transition kernel: buildg -> ifft2 -> ReLU -> fft2 per beta-slice
//     tile entirely in LDS (one kernel instead of four, no g/real round-trip).
//   * Register-tiled matmul (1x4 outputs/thread) with padded buffers.
//   * Adaptive chunk buffer from remaining workspace (capped 64MB).
// ============================================================================

#define PI_D 3.14159265358979323846

__host__ __device__ __forceinline__ int offl_(int l) { return l*(2*l-1)*(2*l+1)/3; }
static inline int Sof(int b) { return b*(4*b*b-1)/3; }           // sum_{l<b}(2l+1)^2
static inline unsigned cdiv(long a, long b) { return (unsigned)((a + b - 1) / b); }

__device__ __constant__ float COS6[6] = {1.f, .5f, -.5f, -1.f, -.5f, .5f};
__device__ __constant__ float SIN6[6] = {0.f, 0.8660254037844386f, 0.8660254037844386f,
                                         0.f, -0.8660254037844386f, -0.8660254037844386f};

// ---------------- table generation ----------------
__global__ void k_lf(double* lf) {
  int n = threadIdx.x;
  double s = 0.0;
  for (int j = 2; j <= n; ++j) s += log((double)j);
  lf[n] = s;
}

__global__ void k_qw(int b, float* out) {
  int k = threadIdx.x, K = 2*b;
  if (k >= K) return;
  double beta = PI_D*(2*k+1)/(4.0*b);
  double s = 0.0;
  for (int j = 0; j < b; ++j)
    s += sin(PI_D*(double)(2*k+1)*(double)(2*j+1)/(4.0*b)) / (double)(2*j+1);
  out[k] = (float)((2.0/b)*sin(beta)*s);
}

// d^l_{m,n}(beta), explicit Jacobi sum, fp64.
// Layout: out[K*offl(l) + k*(2l+1)^2 + (m+l)*(2l+1) + (n+l)]
__global__ void k_wigner(int L, int K, double beta0, const double* __restrict__ lf,
                         float* __restrict__ out) {
  int l = blockIdx.y;
  int d = 2*l+1, dd = d*d;
  long total = (long)K*dd;
  long idx = (long)blockIdx.x*blockDim.x + threadIdx.x;
  if (idx >= total) return;
  int k = (int)(idx / dd), r = (int)(idx % dd);
  int mi = r/d, ni = r - mi*d, m = mi-l, n = ni-l;
  double beta = (K == 1) ? beta0 : PI_D*(double)(2*k+1)/(2.0*K);
  double cb = cos(0.5*beta), sb = sin(0.5*beta);
  double lc = log(cb), ls = log(sb);
  double pref = 0.5*(lf[l+m]+lf[l-m]+lf[l+n]+lf[l-n]);
  int smin = (n-m > 0) ? (n-m) : 0;
  int smax = (l+n < l-m) ? (l+n) : (l-m);
  double sum = 0.0;
  for (int s = smin; s <= smax; ++s) {
    double t = pref - lf[l+n-s] - lf[s] - lf[m-n+s] - lf[l-m-s]
             + (double)(2*l+n-m-2*s)*lc + (double)(m-n+2*s)*ls;
    double e = exp(t);
    sum += ((m-n+s) & 1) ? -e : e;
  }
  out[(long)K*offl_(l) + idx] = (float)sum;
}

// ---------------- s2 front: 1-D forward DFT (centered output) ----------------
__global__ void k_dft1(const float* __restrict__ in, float2* __restrict__ out, int K) {
  __shared__ float row[64];
  int tid = threadIdx.x;
  long base = (long)blockIdx.x * K;
  row[tid] = in[base + tid];
  __syncthreads();
  int i = tid;
  float2 acc = make_float2(0.f, 0.f);
  float c0 = 6.28318530717958647692f / K;
  for (int j = 0; j < K; ++j) {
    int r = (j * ((K + K/2 - i) & (K-1))) & (K-1);
    float s, c; sincosf(c0 * (float)r, &s, &c);
    acc.x += row[j]*c; acc.y += row[j]*s;
  }
  out[base + i] = acc;
}

// ---------------- fused transition kernel ----------------
// Per block: one (signal, beta_k) KxK tile.
//  1. build g tile (standard freq order) from yl + wigner table
//  2. unnormalized inverse FFT2 (Stockham radix-2, LDS)
//  3. ReLU (real part)
//  4. fwd=1: forward FFT2, write complex X (standard order)
//     fwd=0: write real signal
// Stockham DIF: per stage (l half-size, m=K/(2l)):
//   dst[k+2jm] = a+b ; dst[k+2jm+m] = (a-b)*TW[j*m]   (verified N=2,4 by hand)
// TW[t] = e^{-2pi i t/K}; inverse uses conj (fsign=-1 on imag).
__device__ __forceinline__ void fft_axis(float2* T, float2* S, const float2* TW,
                                         int K, int axis, float fsign,
                                         int tid, int bs) {
  const int half = K >> 1;
  int stages = 0; for (int t = K; t > 1; t >>= 1) ++stages;
  for (int b0 = 0; b0 < K; b0 += half) {
    int cur = 0;                       // 0: data in T, 1: in S
    int l = half, m = 1;
    for (int s = 0; s < stages; ++s) {
      for (int t = tid; t < half*half; t += bs) {
        int line = t / half, b = t - (t/half)*half;
        int j = b / m, k = b - (b/m)*m;
        int i0 = k + j*m, i1 = i0 + l*m;
        int o0 = k + 2*j*m, o1 = o0 + m;
        float2 a, bb;
        if (cur == 0) {
          int t0i = axis ? (i0*K + b0 + line) : ((b0+line)*K + i0);
          int t1i = axis ? (i1*K + b0 + line) : ((b0+line)*K + i1);
          a = T[t0i]; bb = T[t1i];
        } else {
          a = S[line*K + i0]; bb = S[line*K + i1];
        }
        float2 w = TW[j*m]; w.y *= fsign;
        float2 dv = make_float2(a.x - bb.x, a.y - bb.y);
        float2 t1 = make_float2(dv.x*w.x - dv.y*w.y, dv.x*w.y + dv.y*w.x);
        float2 t0 = make_float2(a.x + bb.x, a.y + bb.y);
        if (cur == 0) {
          S[line*K + o0] = t0; S[line*K + o1] = t1;
        } else {
          int d0i = axis ? (o0*K + b0 + line) : ((b0+line)*K + o0);
          int d1i = axis ? (o1*K + b0 + line) : ((b0+line)*K + o1);
          T[d0i] = t0; T[d1i] = t1;
        }
      }
      __syncthreads();
      cur ^= 1; l >>= 1; m <<= 1;
    }
    if (cur == 1) {                    // odd #stages: copy S back to T
      for (int t = tid; t < half*K; t += bs) {
        int line = t / K, e = t - (t/K)*K;
        int ti = axis ? (e*K + b0 + line) : ((b0+line)*K + e);
        T[ti] = S[line*K + e];
      }
      __syncthreads();
    }
  }
}

__global__ void k_trans(const float2* __restrict__ yl, int ylS,
                        const float* __restrict__ wig, int Lsyn,
                        float2* __restrict__ outX, float* __restrict__ outR,
                        int K, int fwd) {
  extern __shared__ float2 smc[];
  float2* TW = smc;
  float2* T  = smc + K/2;
  float2* S  = T + K*K;
  const int tid = threadIdx.x, bs = blockDim.x;
  const int ci = blockIdx.x / K, k = blockIdx.x - ci*K;
  const int KK = K*K, Kh = K/2, Km1 = K-1;
  const float c0 = 6.28318530717958647692f / K;
  for (int t = tid; t < Kh; t += bs) {
    float s, c; sincosf(c0 * (float)t, &s, &c);
    TW[t] = make_float2(c, -s);
  }
  // 1. build g tile (standard order)
  for (int idx = tid; idx < KK; idx += bs) {
    int fm = idx / K, fn = idx - (idx/K)*K;
    int m = (fm ^ Kh) - Kh, n = (fn ^ Kh) - Kh;
    int am = m < 0 ? -m : m, an = n < 0 ? -n : n;
    int lmin = am > an ? am : an;
    float2 acc = make_float2(0.f, 0.f);
    for (int l = lmin; l < Lsyn; ++l) {
      int d = 2*l+1;
      int r = (m+l)*d + (n+l);
      float wv = wig[(size_t)K*offl_(l) + (size_t)k*d*d + r];
      float2 yv = yl[(size_t)ci*ylS + offl_(l) + r];
      acc.x += wv*yv.x; acc.y += wv*yv.y;
    }
    T[idx] = acc;
  }
  __syncthreads();
  // 2. inverse FFT2
  fft_axis(T, S, TW, K, 0, -1.f, tid, bs);   // along n (contiguous)
  fft_axis(T, S, TW, K, 1, -1.f, tid, bs);   // along m
  // 3. ReLU
  for (int idx = tid; idx < KK; idx += bs)
    T[idx] = make_float2(fmaxf(T[idx].x, 0.f), 0.f);
  __syncthreads();
  if (fwd) {
    fft_axis(T, S, TW, K, 0, 1.f, tid, bs);
    fft_axis(T, S, TW, K, 1, 1.f, tid, bs);
    float2* o = outX + ((size_t)ci*K + k)*KK;
    for (int idx = tid; idx < KK; idx += bs) o[idx] = T[idx];
  } else {
    float* o = outR + ((size_t)ci*K + k)*KK;
    for (int idx = tid; idx < KK; idx += bs) o[idx] = T[idx].x;
  }
  (void)Km1;
}

// ---------------- Wigner analysis (X in STANDARD freq order) ----------------
__global__ void k_analysis(const float2* __restrict__ X, const float* __restrict__ wig,
                           const float* __restrict__ qw, float2* __restrict__ xh,
                           int BC, int K, int Sstride) {
  int l = blockIdx.y, d = 2*l+1, dd = d*d;
  long total = (long)BC*dd;
  long idx = (long)blockIdx.x*blockDim.x + threadIdx.x;
  if (idx >= total) return;
  int bc = (int)(idx / dd), r = (int)(idx % dd);
  int mi = r/d, ni = r - mi*d, m = mi-l, n = ni-l;
  const float* wl = wig + (long)K*offl_(l);
  int fm = (m + K) & (K-1), fn = (n + K) & (K-1);
  const float2* Xp = X + (long)bc*K*K*K + (long)fm*K + fn;
  float2 acc = make_float2(0.f, 0.f);
  for (int k = 0; k < K; ++k) {
    float w = qw[k] * wl[(long)k*dd + r];
    float2 xv = Xp[(long)k*K*K];
    acc.x += w*xv.x; acc.y += w*xv.y;
  }
  xh[(long)bc*Sstride + offl_(l) + r] = acc;
}

// s2 variant: XS2 is CENTERED (from k_dft1). stride 1024, offset l^2.
__global__ void k_analysis_s2(const float2* __restrict__ X, const float* __restrict__ wig,
                              const float* __restrict__ qw, float2* __restrict__ xh,
                              int BC, int K) {
  int l = blockIdx.y, d = 2*l+1, dd = d*d;
  long total = (long)BC*d;
  long idx = (long)blockIdx.x*blockDim.x + threadIdx.x;
  if (idx >= total) return;
  int bc = (int)(idx / d), mi = (int)(idx % d), m = mi - l;
  const float* wl = wig + (long)K*offl_(l);
  float2 acc = make_float2(0.f, 0.f);
  for (int k = 0; k < K; ++k) {
    float w = qw[k] * wl[(long)k*dd + mi*d + l];
    float2 xv = X[((long)bc*K + k)*K + (K/2+m)];
    acc.x += w*xv.x; acc.y += w*xv.y;
  }
  xh[(long)bc*1024 + l*l + mi] = acc;
}

// ---------------- spectral kernels from weights (l-grouped) ----------------
__global__ void k_kh(const float* __restrict__ w, const float* __restrict__ d0,
                     float2* __restrict__ kh, int C, int F, int l0, int koff0, int Sg) {
  int l = blockIdx.y + l0, d = 2*l+1, dd = d*d;
  long total = (long)C*F*dd;
  long idx = (long)blockIdx.x*blockDim.x + threadIdx.x;
  if (idx >= total) return;
  int cf = (int)(idx / dd), r = (int)(idx % dd);
  int mi = r/d, ni = r - mi*d, m = mi-l, n = ni-l;
  const float* wp = w + (long)cf*36;
  float re = 0.f, im = 0.f;
  for (int a = 0; a < 6; ++a) {
    int pa = ((m*a) % 6 + 6) % 6;
    for (int g = 0; g < 6; ++g) {
      int p = (pa + ((n*g) % 6 + 6) % 6) % 6;
      float wv = wp[a*6 + g];
      re += wv*COS6[p]; im += wv*SIN6[p];
    }
  }
  float dv = d0[offl_(l) + r];
  kh[(long)cf*Sg + (offl_(l) - koff0) + r] = make_float2(re*dv, im*dv);
}

__global__ void k_kh_s2(const float* __restrict__ w, const float* __restrict__ d0,
                        float2* __restrict__ kh, int C, int F) {
  int l = blockIdx.y, d = 2*l+1;
  long total = (long)C*F*d;
  long idx = (long)blockIdx.x*blockDim.x + threadIdx.x;
  if (idx >= total) return;
  int cf = (int)(idx / d), mi = (int)(idx % d), m = mi - l;
  const float* wp = w + (long)cf*6;
  float re = 0.f, im = 0.f;
  for (int j = 0; j < 6; ++j) {
    int p = ((-m*j) % 6 + 6) % 6;
    re += wp[j]*COS6[p]; im += wp[j]*SIN6[p];
  }
  float dv = d0[offl_(l) + mi*d + l];
  kh[(long)cf*1024 + l*l + mi] = make_float2(re*dv, im*dv);
}

// s2 rank-1: yl[b,f,m,n] = sum_c xh[b,c,m]*kh[c,f,n]
__global__ void k_rank1(const float2* __restrict__ xh, const float2* __restrict__ kh,
                        float2* __restrict__ yl, int B, int C, int F, int Sout) {
  int l = blockIdx.y, d = 2*l+1, dd = d*d;
  long total = (long)B*F*dd;
  long idx = (long)blockIdx.x*blockDim.x + threadIdx.x;
  if (idx >= total) return;
  int bf = (int)(idx / dd), r = (int)(idx % dd);
  int b = bf / F, f = bf - b*F;
  int mi = r/d, ni = r - mi*d;
  float2 acc = make_float2(0.f, 0.f);
  for (int c = 0; c < C; ++c) {
    float2 xv = xh[((long)b*C + c)*1024 + l*l + mi];
    float2 kv = kh[((long)c*F + f)*1024 + l*l + ni];
    acc.x += xv.x*kv.x - xv.y*kv.y;
    acc.y += xv.x*kv.y + xv.y*kv.x;
  }
  yl[(long)bf*Sout + offl_(l) + r] = acc;
}

// per-degree complex matmul, register-tiled 1x4 (buffers padded; stores guarded)
__global__ void k_matmul4(const float2* __restrict__ xh, int xhS,
                          const float2* __restrict__ kh, int khS, int koff0, int l0,
                          float2* __restrict__ yl, int ylS,
                          int B, int C, int F, int accf) {
  int l = blockIdx.y + l0, d = 2*l+1;
  int nt = (d + 3) >> 2;
  long total = (long)B*F*d*nt;
  long idx = (long)blockIdx.x*blockDim.x + threadIdx.x;
  if (idx >= total) return;
  int t  = (int)(idx % nt); long r1 = idx / nt;
  int mi = (int)(r1 % d);   long r2 = r1 / d;
  int f  = (int)(r2 % F);   int b  = (int)(r2 / F);
  int ni0 = t*4;
  int ol = offl_(l), olk = ol - koff0;
  float2 a0{0,0}, a1{0,0}, a2{0,0}, a3{0,0};
  for (int c = 0; c < C; ++c) {
    const float2* xr = xh + ((size_t)b*C + c)*xhS + ol + (size_t)mi*d;
    const float2* kr = kh + ((size_t)c*F + f)*khS + olk + ni0;
    for (int p = 0; p < d; ++p) {
      float2 xv = xr[p];
      const float2* kp = kr + (size_t)p*d;
      float2 k0 = kp[0], k1 = kp[1], k2 = kp[2], k3 = kp[3];  // pad-covered
      a0.x += xv.x*k0.x - xv.y*k0.y; a0.y += xv.x*k0.y + xv.y*k0.x;
      a1.x += xv.x*k1.x - xv.y*k1.y; a1.y += xv.x*k1.y + xv.y*k1.x;
      a2.x += xv.x*k2.x - xv.y*k2.y; a2.y += xv.x*k2.y + xv.y*k2.x;
      a3.x += xv.x*k3.x - xv.y*k3.y; a3.y += xv.x*k3.y + xv.y*k3.x;
    }
  }
  float2* o = yl + ((size_t)b*F + f)*ylS + ol + (size_t)mi*d + ni0;
  int rem = d - ni0;
  if (accf) {
    { float2 v = o[0]; v.x += a0.x; v.y += a0.y; o[0] = v; }
    if (rem > 1) { float2 v = o[1]; v.x += a1.x; v.y += a1.y; o[1] = v; }
    if (rem > 2) { float2 v = o[2]; v.x += a2.x; v.y += a2.y; o[2] = v; }
    if (rem > 3) { float2 v = o[3]; v.x += a3.x; v.y += a3.y; o[3] = v; }
  } else {
    o[0] = a0;
    if (rem > 1) o[1] = a1;
    if (rem > 2) o[2] = a2;
    if (rem > 3) o[3] = a3;
  }
}

// integrate over SO(3) at b=2 + linear head
__global__ void k_final(const float* __restrict__ h, const float* __restrict__ qw,
                        const float* __restrict__ lw, const float* __restrict__ lb,
                        float* __restrict__ out) {
  int b = blockIdx.x, f = threadIdx.x;
  const float* hp = h + ((long)b*256 + f)*64;
  float s = 0.f;
  for (int k = 0; k < 4; ++k) {
    float q = qw[k];
    for (int ag = 0; ag < 16; ++ag) s += hp[k*16 + ag]*q;
  }
  s = s * 0.0625f * lw[f];
  __shared__ float red[256];
  red[f] = s; __syncthreads();
  for (int st = 128; st > 0; st >>= 1) {
    if (f < st) red[f] += red[f + st];
    __syncthreads();
  }
  if (f == 0) out[b] = red[0] + lb[0];
}

// ============================================================================
extern "C" void kernel_launch(void* const* d_in, const int* in_sizes, int n_in,
                              void* d_out, int out_size, void* d_ws, size_t ws_size,
                              hipStream_t stream) {
  (void)in_sizes; (void)n_in;
  const float* x   = (const float*)d_in[0];
  const float* ks2 = (const float*)d_in[1];
  const float* lw  = (const float*)d_in[14];
  const float* lb  = (const float*)d_in[15];
  float* out = (float*)d_out;

  const int bl[5] = {32, 16, 8, 4, 2};
  char* ws = (char*)d_ws;
  size_t off = 0;
  auto alloc = [&](size_t nbytes) -> char* {
    char* p = ws + off;
    off += (nbytes + 255) & ~(size_t)255;
    return p;
  };

  double* lf = (double*)alloc(64*sizeof(double));
  float* qwT[5]; float* wigT[5]; float* d0T[4];
  for (int i = 0; i < 5; ++i) qwT[i]  = (float*)alloc((size_t)2*bl[i]*4);
  for (int i = 0; i < 5; ++i) wigT[i] = (float*)alloc((size_t)2*bl[i]*Sof(bl[i])*4);
  for (int i = 0; i < 4; ++i) d0T[i]  = (float*)alloc((size_t)Sof(bl[i])*4);

  const size_t KHCAP = 12u<<20;
  float2* KH  = (float2*)alloc(KHCAP + 4096);           // +pad for 1x4 tiles
  float2* XH  = (float2*)alloc((size_t)64*43680*8 + 4096);
  float2* YL  = (float2*)alloc((size_t)64*43680*8 + 4096);
  float2* XHA = (float2*)alloc((size_t)64*5456*8 + 4096);
  float2* XS2 = (float2*)alloc((size_t)1024*64*8);
  float2* XHS = (float2*)alloc((size_t)16*1024*8);
  float2* KHS = (float2*)alloc((size_t)64*1024*8);
  float*  OUTS= (float*)alloc((size_t)1024*64*4);
  // remaining workspace -> chunk buffer G (X spectra), capped 64MB
  size_t remain = (ws_size > off) ? (ws_size - off) : 0;
  size_t GCAP = remain > (64u<<20) ? (64u<<20) : (remain & ~(size_t)255);
  if (GCAP < (3u<<20)) {                       // cannot even hold one K=64 signal
    hipMemsetAsync(d_out, 0, (size_t)out_size*sizeof(float), stream);
    return;
  }
  float2* G = (float2*)alloc(GCAP);

  // ---- tables ----
  k_lf<<<1, 64, 0, stream>>>(lf);
  for (int i = 0; i < 5; ++i) k_qw<<<1, 64, 0, stream>>>(bl[i], qwT[i]);
  for (int i = 0; i < 5; ++i) {
    int L = bl[i], K = 2*L, md = 2*L-1;
    k_wigner<<<dim3(cdiv((long)K*md*md, 256), L), 256, 0, stream>>>(L, K, 0.0, lf, wigT[i]);
  }
  const double b0s[4] = {PI_D/16, PI_D/8, PI_D/4, PI_D/2};
  for (int i = 0; i < 4; ++i) {
    int L = bl[i], md = 2*L-1;
    k_wigner<<<dim3(cdiv((long)md*md, 256), L), 256, 0, stream>>>(L, 1, b0s[i], lf, d0T[i]);
  }

  // fused transition: yl -> [buildg+ifft2+relu+fft2] -> X chunks -> analysis -> xh
  auto transition = [&](const float2* yl, int ylS, int Lsyn, const float* wsyn,
                        int K, const float* wana, const float* qana,
                        int Lana, int Sana, float2* xh_out, int nsig) {
    long perX = (long)K*K*K;
    int CH = (int)((long)(GCAP/8)/perX);
    if (CH > nsig) CH = nsig;
    if (CH < 1) CH = 1;
    size_t lds = sizeof(float2)*((size_t)K/2 + (size_t)K*K + (size_t)K*K/2);
    int dd = (2*Lana-1)*(2*Lana-1);
    for (int s0 = 0; s0 < nsig; s0 += CH) {
      int ch = (nsig - s0 < CH) ? (nsig - s0) : CH;
      k_trans<<<ch*K, 256, lds, stream>>>(yl + (size_t)s0*ylS, ylS, wsyn, Lsyn,
                                          G, nullptr, K, 1);
      k_analysis<<<dim3(cdiv((long)ch*dd, 256), Lana), 256, 0, stream>>>(
          G, wana, qana, xh_out + (size_t)s0*Sana, ch, K, Sana);
    }
  };

  // kh built in degree groups through KH, matmul'd immediately
  auto conv_matmul = [&](const float* w, const float* d0, const float2* xh, int xhS,
                         float2* yl, int ylS, int B, int C, int F, int L, int accf) {
    int l0 = 0;
    while (l0 < L) {
      int l1 = l0; long sg = 0;
      while (l1 < L) {
        long dd = (long)(2*l1+1)*(2*l1+1);
        if (l1 > l0 && (size_t)C*F*(size_t)(sg+dd)*8 > KHCAP) break;
        sg += dd; ++l1;
      }
      int koff0 = offl_(l0);
      int dmax = 2*(l1-1)+1, ddmax = dmax*dmax;
      int ntmax = (dmax + 3) >> 2;
      k_kh<<<dim3(cdiv((long)C*F*ddmax, 256), l1-l0), 256, 0, stream>>>(
          w, d0, KH, C, F, l0, koff0, (int)sg);
      k_matmul4<<<dim3(cdiv((long)B*F*dmax*ntmax, 256), l1-l0), 256, 0, stream>>>(
          xh, xhS, KH, (int)sg, koff0, l0, yl, ylS, B, C, F, accf);
      l0 = l1;
    }
  };

  // ---- s2 conv (b=32) -> transition -> XH for block 1 ----
  k_dft1<<<1024, 64, 0, stream>>>(x, XS2, 64);
  k_analysis_s2<<<dim3(cdiv(16L*63, 256), 32), 256, 0, stream>>>(XS2, wigT[0], qwT[0], XHS, 16, 64);
  k_kh_s2<<<dim3(cdiv(64L*63, 256), 32), 256, 0, stream>>>(ks2, d0T[0], KHS, 4, 16);
  k_rank1<<<dim3(cdiv(64L*3969, 256), 32), 256, 0, stream>>>(XHS, KHS, YL, 4, 4, 16, 43680);
  transition(YL, 43680, 32, wigT[0], 64, wigT[0], qwT[0], 32, 43680, XH, 64);

  // ---- residual blocks ----
  const float* wa_[4] = {(const float*)d_in[2], (const float*)d_in[5], (const float*)d_in[8],  (const float*)d_in[11]};
  const float* wb_[4] = {(const float*)d_in[3], (const float*)d_in[6], (const float*)d_in[9],  (const float*)d_in[12]};
  const float* wsn[4] = {(const float*)d_in[4], (const float*)d_in[7], (const float*)d_in[10], (const float*)d_in[13]};
  const int Cs[4] = {16, 32, 64, 128}, Fs[4] = {32, 64, 128, 256};

  for (int blk = 0; blk < 4; ++blk) {
    const int bw = bl[blk], C = Cs[blk], F = Fs[blk], B = 4;
    const int L = bw, Lh = bw/2, K = 2*bw, Kh = bw;
    const int Sa = Sof(L), Sh = Sof(Lh);

    // a-conv: yl_a = xh_in @ kh_a
    conv_matmul(wa_[blk], d0T[blk], XH, Sa, YL, Sa, B, C, C, L, 0);
    // ha transition (synthesis at L on K grid, analyze Lh)
    transition(YL, Sa, L, wigT[blk], K, wigT[blk], qwT[blk], Lh, Sh, XHA, B*C);
    // b-conv + shortcut
    conv_matmul(wb_[blk], d0T[blk], XHA, Sh, YL, Sh, B, C, F, Lh, 0);
    conv_matmul(wsn[blk], d0T[blk], XH, Sa, YL, Sh, B, C, F, Lh, 1);

    if (blk < 3) {
      transition(YL, Sh, Lh, wigT[blk+1], Kh, wigT[blk+1], qwT[blk+1], Lh, Sh, XH, B*F);
    } else {
      // final: synthesize + ifft2 + relu, write real signals (K=4)
      size_t lds = sizeof(float2)*((size_t)Kh/2 + (size_t)Kh*Kh + (size_t)Kh*Kh/2);
      k_trans<<<B*F*Kh, 256, lds, stream>>>(YL, Sh, wigT[4], Lh, nullptr, OUTS, Kh, 0);
    }
  }

  // ---- integrate (b=2) + linear head ----
  k_final<<<4, 256, 0, stream>>>(OUTS, qwT[4], lw, lb, out);
}

// Round 4
// 5851.070 us; speedup vs baseline: 2.6587x; 1.9386x over previous
//
#include <hip/hip_runtime.h>
#include <math.h>

// ============================================================================
// S2CNN regression — round 3.
//  R2 profile: k_matmul4 latency-bound (occ 1.2%, VALU 1.1%, 35GB fetched);
//  k_trans had 1.0e8 LDS bank conflicts (32-way on axis-1 FFT butterflies).
//  This round:
//   * Per-degree complex GEMM (LDS-tiled 32x64x16, 2x4 regs/thread), one
//     launch per conv over all l (grid.y = l).
//   * kh computed on the fly inside the GEMM B-load from a 6x6 phase table
//     Wf (exact: alpha/gamma grids are multiples of 2*pi/6).
//   * FFT tile padded to pitch K+1 -> axis-1 butterflies conflict-free.
// ============================================================================

#define PI_D 3.14159265358979323846

__host__ __device__ __forceinline__ int offl_(int l) { return l*(2*l-1)*(2*l+1)/3; }
static inline int Sof(int b) { return b*(4*b*b-1)/3; }           // sum_{l<b}(2l+1)^2
static inline unsigned cdiv(long a, long b) { return (unsigned)((a + b - 1) / b); }

__device__ __constant__ float COS6[6] = {1.f, .5f, -.5f, -1.f, -.5f, .5f};
__device__ __constant__ float SIN6[6] = {0.f, 0.8660254037844386f, 0.8660254037844386f,
                                         0.f, -0.8660254037844386f, -0.8660254037844386f};

// ---------------- table generation ----------------
__global__ void k_lf(double* lf) {
  int n = threadIdx.x;
  double s = 0.0;
  for (int j = 2; j <= n; ++j) s += log((double)j);
  lf[n] = s;
}

__global__ void k_qw(int b, float* out) {
  int k = threadIdx.x, K = 2*b;
  if (k >= K) return;
  double beta = PI_D*(2*k+1)/(4.0*b);
  double s = 0.0;
  for (int j = 0; j < b; ++j)
    s += sin(PI_D*(double)(2*k+1)*(double)(2*j+1)/(4.0*b)) / (double)(2*j+1);
  out[k] = (float)((2.0/b)*sin(beta)*s);
}

// d^l_{m,n}(beta), explicit Jacobi sum, fp64.
// Layout: out[K*offl(l) + k*(2l+1)^2 + (m+l)*(2l+1) + (n+l)]
__global__ void k_wigner(int L, int K, double beta0, const double* __restrict__ lf,
                         float* __restrict__ out) {
  int l = blockIdx.y;
  int d = 2*l+1, dd = d*d;
  long total = (long)K*dd;
  long idx = (long)blockIdx.x*blockDim.x + threadIdx.x;
  if (idx >= total) return;
  int k = (int)(idx / dd), r = (int)(idx % dd);
  int mi = r/d, ni = r - mi*d, m = mi-l, n = ni-l;
  double beta = (K == 1) ? beta0 : PI_D*(double)(2*k+1)/(2.0*K);
  double cb = cos(0.5*beta), sb = sin(0.5*beta);
  double lc = log(cb), ls = log(sb);
  double pref = 0.5*(lf[l+m]+lf[l-m]+lf[l+n]+lf[l-n]);
  int smin = (n-m > 0) ? (n-m) : 0;
  int smax = (l+n < l-m) ? (l+n) : (l-m);
  double sum = 0.0;
  for (int s = smin; s <= smax; ++s) {
    double t = pref - lf[l+n-s] - lf[s] - lf[m-n+s] - lf[l-m-s]
             + (double)(2*l+n-m-2*s)*lc + (double)(m-n+2*s)*ls;
    double e = exp(t);
    sum += ((m-n+s) & 1) ? -e : e;
  }
  out[(long)K*offl_(l) + idx] = (float)sum;
}

// ---------------- s2 front: 1-D forward DFT (centered output) ----------------
__global__ void k_dft1(const float* __restrict__ in, float2* __restrict__ out, int K) {
  __shared__ float row[64];
  int tid = threadIdx.x;
  long base = (long)blockIdx.x * K;
  row[tid] = in[base + tid];
  __syncthreads();
  int i = tid;
  float2 acc = make_float2(0.f, 0.f);
  float c0 = 6.28318530717958647692f / K;
  for (int j = 0; j < K; ++j) {
    int r = (j * ((K + K/2 - i) & (K-1))) & (K-1);
    float s, c; sincosf(c0 * (float)r, &s, &c);
    acc.x += row[j]*c; acc.y += row[j]*s;
  }
  out[base + i] = acc;
}

// ---------------- fused transition kernel ----------------
// T tile is padded to pitch P=K+1 so axis-1 (column) butterflies are
// conflict-free (stride 65 float2 -> 2-way bank aliasing = free).
__device__ __forceinline__ void fft_axis(float2* T, int P, float2* S, const float2* TW,
                                         int K, int axis, float fsign,
                                         int tid, int bs) {
  const int half = K >> 1;
  int stages = 0; for (int t = K; t > 1; t >>= 1) ++stages;
  for (int b0 = 0; b0 < K; b0 += half) {
    int cur = 0;                       // 0: data in T, 1: in S
    int l = half, m = 1;
    for (int s = 0; s < stages; ++s) {
      for (int t = tid; t < half*half; t += bs) {
        int line = t / half, b = t - (t/half)*half;
        int j = b / m, k = b - (b/m)*m;
        int i0 = k + j*m, i1 = i0 + l*m;
        int o0 = k + 2*j*m, o1 = o0 + m;
        float2 a, bb;
        if (cur == 0) {
          int t0i = axis ? (i0*P + b0 + line) : ((b0+line)*P + i0);
          int t1i = axis ? (i1*P + b0 + line) : ((b0+line)*P + i1);
          a = T[t0i]; bb = T[t1i];
        } else {
          a = S[line*K + i0]; bb = S[line*K + i1];
        }
        float2 w = TW[j*m]; w.y *= fsign;
        float2 dv = make_float2(a.x - bb.x, a.y - bb.y);
        float2 t1 = make_float2(dv.x*w.x - dv.y*w.y, dv.x*w.y + dv.y*w.x);
        float2 t0 = make_float2(a.x + bb.x, a.y + bb.y);
        if (cur == 0) {
          S[line*K + o0] = t0; S[line*K + o1] = t1;
        } else {
          int d0i = axis ? (o0*P + b0 + line) : ((b0+line)*P + o0);
          int d1i = axis ? (o1*P + b0 + line) : ((b0+line)*P + o1);
          T[d0i] = t0; T[d1i] = t1;
        }
      }
      __syncthreads();
      cur ^= 1; l >>= 1; m <<= 1;
    }
    if (cur == 1) {                    // odd #stages: copy S back to T
      for (int t = tid; t < half*K; t += bs) {
        int line = t / K, e = t - (t/K)*K;
        int ti = axis ? (e*P + b0 + line) : ((b0+line)*P + e);
        T[ti] = S[line*K + e];
      }
      __syncthreads();
    }
  }
}

__global__ void k_trans(const float2* __restrict__ yl, int ylS,
                        const float* __restrict__ wig, int Lsyn,
                        float2* __restrict__ outX, float* __restrict__ outR,
                        int K, int fwd) {
  extern __shared__ float2 smc[];
  const int P = K + 1;
  float2* TW = smc;
  float2* T  = smc + K/2;
  float2* S  = T + K*P;
  const int tid = threadIdx.x, bs = blockDim.x;
  const int ci = blockIdx.x / K, k = blockIdx.x - ci*K;
  const int KK = K*K, Kh = K/2;
  const float c0 = 6.28318530717958647692f / K;
  for (int t = tid; t < Kh; t += bs) {
    float s, c; sincosf(c0 * (float)t, &s, &c);
    TW[t] = make_float2(c, -s);
  }
  // 1. build g tile (standard freq order)
  for (int idx = tid; idx < KK; idx += bs) {
    int fm = idx / K, fn = idx - (idx/K)*K;
    int m = (fm ^ Kh) - Kh, n = (fn ^ Kh) - Kh;
    int am = m < 0 ? -m : m, an = n < 0 ? -n : n;
    int lmin = am > an ? am : an;
    float2 acc = make_float2(0.f, 0.f);
    for (int l = lmin; l < Lsyn; ++l) {
      int d = 2*l+1;
      int r = (m+l)*d + (n+l);
      float wv = wig[(size_t)K*offl_(l) + (size_t)k*d*d + r];
      float2 yv = yl[(size_t)ci*ylS + offl_(l) + r];
      acc.x += wv*yv.x; acc.y += wv*yv.y;
    }
    T[fm*P + fn] = acc;
  }
  __syncthreads();
  // 2. inverse FFT2
  fft_axis(T, P, S, TW, K, 0, -1.f, tid, bs);
  fft_axis(T, P, S, TW, K, 1, -1.f, tid, bs);
  // 3. ReLU
  for (int idx = tid; idx < KK; idx += bs) {
    int fm = idx / K, fn = idx - (idx/K)*K;
    T[fm*P + fn] = make_float2(fmaxf(T[fm*P + fn].x, 0.f), 0.f);
  }
  __syncthreads();
  if (fwd) {
    fft_axis(T, P, S, TW, K, 0, 1.f, tid, bs);
    fft_axis(T, P, S, TW, K, 1, 1.f, tid, bs);
    float2* o = outX + ((size_t)ci*K + k)*KK;
    for (int idx = tid; idx < KK; idx += bs)
      o[idx] = T[(idx/K)*P + (idx - (idx/K)*K)];
  } else {
    float* o = outR + ((size_t)ci*K + k)*KK;
    for (int idx = tid; idx < KK; idx += bs)
      o[idx] = T[(idx/K)*P + (idx - (idx/K)*K)].x;
  }
}

// ---------------- Wigner analysis (X in STANDARD freq order) ----------------
__global__ void k_analysis(const float2* __restrict__ X, const float* __restrict__ wig,
                           const float* __restrict__ qw, float2* __restrict__ xh,
                           int BC, int K, int Sstride) {
  int l = blockIdx.y, d = 2*l+1, dd = d*d;
  long total = (long)BC*dd;
  long idx = (long)blockIdx.x*blockDim.x + threadIdx.x;
  if (idx >= total) return;
  int bc = (int)(idx / dd), r = (int)(idx % dd);
  int mi = r/d, ni = r - mi*d, m = mi-l, n = ni-l;
  const float* wl = wig + (long)K*offl_(l);
  int fm = (m + K) & (K-1), fn = (n + K) & (K-1);
  const float2* Xp = X + (long)bc*K*K*K + (long)fm*K + fn;
  float2 acc = make_float2(0.f, 0.f);
  for (int k = 0; k < K; ++k) {
    float w = qw[k] * wl[(long)k*dd + r];
    float2 xv = Xp[(long)k*K*K];
    acc.x += w*xv.x; acc.y += w*xv.y;
  }
  xh[(long)bc*Sstride + offl_(l) + r] = acc;
}

// s2 variant: XS2 is CENTERED (from k_dft1). stride 1024, offset l^2.
__global__ void k_analysis_s2(const float2* __restrict__ X, const float* __restrict__ wig,
                              const float* __restrict__ qw, float2* __restrict__ xh,
                              int BC, int K) {
  int l = blockIdx.y, d = 2*l+1, dd = d*d;
  long total = (long)BC*d;
  long idx = (long)blockIdx.x*blockDim.x + threadIdx.x;
  if (idx >= total) return;
  int bc = (int)(idx / d), mi = (int)(idx % d), m = mi - l;
  const float* wl = wig + (long)K*offl_(l);
  float2 acc = make_float2(0.f, 0.f);
  for (int k = 0; k < K; ++k) {
    float w = qw[k] * wl[(long)k*dd + mi*d + l];
    float2 xv = X[((long)bc*K + k)*K + (K/2+m)];
    acc.x += w*xv.x; acc.y += w*xv.y;
  }
  xh[(long)bc*1024 + l*l + mi] = acc;
}

// ---------------- 6x6 phase table of the SO(3) conv weights ----------------
// Wf[cf][mm][nn] = sum_{a,g} w[cf,a*6+g] * e^{i*2pi(mm*a+nn*g)/6}
__global__ void k_wf(const float* __restrict__ w, float2* __restrict__ wf, int CF) {
  long idx = (long)blockIdx.x*blockDim.x + threadIdx.x;
  if (idx >= (long)CF*36) return;
  int cf = (int)(idx / 36), r = (int)(idx % 36);
  int mm = r / 6, nn = r - (r/6)*6;
  const float* wp = w + (long)cf*36;
  float re = 0.f, im = 0.f;
  for (int a = 0; a < 6; ++a) {
    int pa = (mm*a) % 6;
    for (int g = 0; g < 6; ++g) {
      int p = (pa + nn*g) % 6;
      float wv = wp[a*6 + g];
      re += wv*COS6[p]; im += wv*SIN6[p];
    }
  }
  wf[idx] = make_float2(re, im);
}

// s2: kh[cf, l^2+mi] = d^l_{m,0}(b0) * sum_j w[cf,j] e^{-i m alpha_j}
__global__ void k_kh_s2(const float* __restrict__ w, const float* __restrict__ d0,
                        float2* __restrict__ kh, int C, int F) {
  int l = blockIdx.y, d = 2*l+1;
  long total = (long)C*F*d;
  long idx = (long)blockIdx.x*blockDim.x + threadIdx.x;
  if (idx >= total) return;
  int cf = (int)(idx / d), mi = (int)(idx % d), m = mi - l;
  const float* wp = w + (long)cf*6;
  float re = 0.f, im = 0.f;
  for (int j = 0; j < 6; ++j) {
    int p = ((-m*j) % 6 + 6) % 6;
    re += wp[j]*COS6[p]; im += wp[j]*SIN6[p];
  }
  float dv = d0[offl_(l) + mi*d + l];
  kh[(long)cf*1024 + l*l + mi] = make_float2(re*dv, im*dv);
}

// s2 rank-1: yl[b,f,m,n] = sum_c xh[b,c,m]*kh[c,f,n]
__global__ void k_rank1(const float2* __restrict__ xh, const float2* __restrict__ kh,
                        float2* __restrict__ yl, int B, int C, int F, int Sout) {
  int l = blockIdx.y, d = 2*l+1, dd = d*d;
  long total = (long)B*F*dd;
  long idx = (long)blockIdx.x*blockDim.x + threadIdx.x;
  if (idx >= total) return;
  int bf = (int)(idx / dd), r = (int)(idx % dd);
  int b = bf / F, f = bf - b*F;
  int mi = r/d, ni = r - mi*d;
  float2 acc = make_float2(0.f, 0.f);
  for (int c = 0; c < C; ++c) {
    float2 xv = xh[((long)b*C + c)*1024 + l*l + mi];
    float2 kv = kh[((long)c*F + f)*1024 + l*l + ni];
    acc.x += xv.x*kv.x - xv.y*kv.y;
    acc.y += xv.x*kv.y + xv.y*kv.x;
  }
  yl[(long)bf*Sout + offl_(l) + r] = acc;
}

// ---------------- per-degree complex GEMM ----------------
// yl[b,f,ol+mi*d+ni] (+)= sum_{c,p} xh[b,c,ol+mi*d+p] * (d0[ol+p*d+ni]*Wf[cf][p-l][ni-l])
// M = B*d (r=b*d+mi), N = F*d (q=f*d+ni), KD = C*d (t=c*d+p).
#define GTM 32
#define GTN 64
#define GTK 16
__global__ __launch_bounds__(256)
void k_gemm(const float2* __restrict__ xh, int xhS,
            const float* __restrict__ d0, const float2* __restrict__ wf,
            float2* __restrict__ yl, int ylS,
            int B, int C, int F, int accf) {
  const int l = blockIdx.y, d = 2*l+1, ol = offl_(l);
  const int M = B*d, N = F*d, KD = C*d;
  const int tn_cnt = (N + GTN - 1)/GTN;
  const int tm_cnt = (M + GTM - 1)/GTM;
  const int tile = blockIdx.x;
  if (tile >= tm_cnt*tn_cnt) return;
  const int tm = tile / tn_cnt, tn = tile - tm*tn_cnt;
  const int r0 = tm*GTM, q0 = tn*GTN;
  __shared__ float2 As[GTK][GTM];
  __shared__ float2 Bs[GTK][GTN];
  const int tid = threadIdx.x;
  const int tx = tid & 15, ty = tid >> 4;
  float2 acc[2][4];
  for (int i = 0; i < 2; ++i)
    for (int j = 0; j < 4; ++j) acc[i][j] = make_float2(0.f, 0.f);

  for (int kt = 0; kt < KD; kt += GTK) {
    for (int idx = tid; idx < GTM*GTK; idx += 256) {
      int kk = idx / GTM, rr = idx - (idx/GTM)*GTM;
      int r = r0 + rr, t = kt + kk;
      float2 v = make_float2(0.f, 0.f);
      if (r < M && t < KD) {
        int b = r / d, mi = r - b*d;
        int c = t / d, p = t - c*d;
        v = xh[((size_t)b*C + c)*xhS + ol + (size_t)mi*d + p];
      }
      As[kk][rr] = v;
    }
    for (int idx = tid; idx < GTN*GTK; idx += 256) {
      int kk = idx / GTN, qq = idx - (idx/GTN)*GTN;
      int q = q0 + qq, t = kt + kk;
      float2 v = make_float2(0.f, 0.f);
      if (q < N && t < KD) {
        int f = q / d, ni = q - f*d;
        int c = t / d, p = t - c*d;
        int mm = (p - l) % 6; if (mm < 0) mm += 6;
        int nn = (ni - l) % 6; if (nn < 0) nn += 6;
        float dv = d0[ol + (size_t)p*d + ni];
        float2 wv = wf[((size_t)c*F + f)*36 + mm*6 + nn];
        v = make_float2(wv.x*dv, wv.y*dv);
      }
      Bs[kk][qq] = v;
    }
    __syncthreads();
    for (int kk = 0; kk < GTK; ++kk) {
      float2 a0 = As[kk][ty],      a1 = As[kk][ty+16];
      float2 b0 = Bs[kk][tx],      b1 = Bs[kk][tx+16];
      float2 b2 = Bs[kk][tx+32],   b3 = Bs[kk][tx+48];
      acc[0][0].x += a0.x*b0.x - a0.y*b0.y; acc[0][0].y += a0.x*b0.y + a0.y*b0.x;
      acc[0][1].x += a0.x*b1.x - a0.y*b1.y; acc[0][1].y += a0.x*b1.y + a0.y*b1.x;
      acc[0][2].x += a0.x*b2.x - a0.y*b2.y; acc[0][2].y += a0.x*b2.y + a0.y*b2.x;
      acc[0][3].x += a0.x*b3.x - a0.y*b3.y; acc[0][3].y += a0.x*b3.y + a0.y*b3.x;
      acc[1][0].x += a1.x*b0.x - a1.y*b0.y; acc[1][0].y += a1.x*b0.y + a1.y*b0.x;
      acc[1][1].x += a1.x*b1.x - a1.y*b1.y; acc[1][1].y += a1.x*b1.y + a1.y*b1.x;
      acc[1][2].x += a1.x*b2.x - a1.y*b2.y; acc[1][2].y += a1.x*b2.y + a1.y*b2.x;
      acc[1][3].x += a1.x*b3.x - a1.y*b3.y; acc[1][3].y += a1.x*b3.y + a1.y*b3.x;
    }
    __syncthreads();
  }

  for (int i = 0; i < 2; ++i) {
    int r = r0 + ty + 16*i;
    if (r >= M) continue;
    int b = r / d, mi = r - b*d;
    for (int j = 0; j < 4; ++j) {
      int q = q0 + tx + 16*j;
      if (q >= N) continue;
      int f = q / d, ni = q - f*d;
      float2* o = yl + ((size_t)b*F + f)*ylS + ol + (size_t)mi*d + ni;
      if (accf) { float2 v = *o; v.x += acc[i][j].x; v.y += acc[i][j].y; *o = v; }
      else *o = acc[i][j];
    }
  }
}

// integrate over SO(3) at b=2 + linear head
__global__ void k_final(const float* __restrict__ h, const float* __restrict__ qw,
                        const float* __restrict__ lw, const float* __restrict__ lb,
                        float* __restrict__ out) {
  int b = blockIdx.x, f = threadIdx.x;
  const float* hp = h + ((long)b*256 + f)*64;
  float s = 0.f;
  for (int k = 0; k < 4; ++k) {
    float q = qw[k];
    for (int ag = 0; ag < 16; ++ag) s += hp[k*16 + ag]*q;
  }
  s = s * 0.0625f * lw[f];
  __shared__ float red[256];
  red[f] = s; __syncthreads();
  for (int st = 128; st > 0; st >>= 1) {
    if (f < st) red[f] += red[f + st];
    __syncthreads();
  }
  if (f == 0) out[b] = red[0] + lb[0];
}

// ============================================================================
extern "C" void kernel_launch(void* const* d_in, const int* in_sizes, int n_in,
                              void* d_out, int out_size, void* d_ws, size_t ws_size,
                              hipStream_t stream) {
  (void)in_sizes; (void)n_in;
  const float* x   = (const float*)d_in[0];
  const float* ks2 = (const float*)d_in[1];
  const float* lw  = (const float*)d_in[14];
  const float* lb  = (const float*)d_in[15];
  float* out = (float*)d_out;

  const int bl[5] = {32, 16, 8, 4, 2};
  char* ws = (char*)d_ws;
  size_t off = 0;
  auto alloc = [&](size_t nbytes) -> char* {
    char* p = ws + off;
    off += (nbytes + 255) & ~(size_t)255;
    return p;
  };

  double* lf = (double*)alloc(64*sizeof(double));
  float* qwT[5]; float* wigT[5]; float* d0T[4];
  for (int i = 0; i < 5; ++i) qwT[i]  = (float*)alloc((size_t)2*bl[i]*4);
  for (int i = 0; i < 5; ++i) wigT[i] = (float*)alloc((size_t)2*bl[i]*Sof(bl[i])*4);
  for (int i = 0; i < 4; ++i) d0T[i]  = (float*)alloc((size_t)Sof(bl[i])*4);

  float2* WF  = (float2*)alloc((size_t)128*256*36*8);   // 6x6 phase tables (max CF)
  float2* XH  = (float2*)alloc((size_t)64*43680*8);
  float2* YL  = (float2*)alloc((size_t)64*43680*8);
  float2* XHA = (float2*)alloc((size_t)64*5456*8);
  float2* XS2 = (float2*)alloc((size_t)1024*64*8);
  float2* XHS = (float2*)alloc((size_t)16*1024*8);
  float2* KHS = (float2*)alloc((size_t)64*1024*8);
  float*  OUTS= (float*)alloc((size_t)1024*64*4);
  size_t remain = (ws_size > off) ? (ws_size - off) : 0;
  size_t GCAP = remain > (64u<<20) ? (64u<<20) : (remain & ~(size_t)255);
  if (GCAP < (3u<<20)) {
    hipMemsetAsync(d_out, 0, (size_t)out_size*sizeof(float), stream);
    return;
  }
  float2* G = (float2*)alloc(GCAP);

  // ---- tables ----
  k_lf<<<1, 64, 0, stream>>>(lf);
  for (int i = 0; i < 5; ++i) k_qw<<<1, 64, 0, stream>>>(bl[i], qwT[i]);
  for (int i = 0; i < 5; ++i) {
    int L = bl[i], K = 2*L, md = 2*L-1;
    k_wigner<<<dim3(cdiv((long)K*md*md, 256), L), 256, 0, stream>>>(L, K, 0.0, lf, wigT[i]);
  }
  const double b0s[4] = {PI_D/16, PI_D/8, PI_D/4, PI_D/2};
  for (int i = 0; i < 4; ++i) {
    int L = bl[i], md = 2*L-1;
    k_wigner<<<dim3(cdiv((long)md*md, 256), L), 256, 0, stream>>>(L, 1, b0s[i], lf, d0T[i]);
  }

  // fused transition: yl -> [buildg+ifft2+relu+fft2] -> X chunks -> analysis -> xh
  auto transition = [&](const float2* yl, int ylS, int Lsyn, const float* wsyn,
                        int K, const float* wana, const float* qana,
                        int Lana, int Sana, float2* xh_out, int nsig) {
    long perX = (long)K*K*K;
    int CH = (int)((long)(GCAP/8)/perX);
    if (CH > nsig) CH = nsig;
    if (CH < 1) CH = 1;
    size_t lds = sizeof(float2)*((size_t)K/2 + (size_t)K*(K+1) + (size_t)K*K/2);
    int dd = (2*Lana-1)*(2*Lana-1);
    for (int s0 = 0; s0 < nsig; s0 += CH) {
      int ch = (nsig - s0 < CH) ? (nsig - s0) : CH;
      k_trans<<<ch*K, 256, lds, stream>>>(yl + (size_t)s0*ylS, ylS, wsyn, Lsyn,
                                          G, nullptr, K, 1);
      k_analysis<<<dim3(cdiv((long)ch*dd, 256), Lana), 256, 0, stream>>>(
          G, wana, qana, xh_out + (size_t)s0*Sana, ch, K, Sana);
    }
  };

  // conv: Wf table + one GEMM launch over all l
  auto conv = [&](const float* w, const float* d0, const float2* xh, int xhS,
                  float2* yl, int ylS, int B, int C, int F, int L, int accf) {
    k_wf<<<cdiv((long)C*F*36, 256), 256, 0, stream>>>(w, WF, C*F);
    int dmax = 2*(L-1)+1;
    int tiles = cdiv((long)B*dmax, GTM) * cdiv((long)F*dmax, GTN);
    k_gemm<<<dim3(tiles, L), 256, 0, stream>>>(xh, xhS, d0, WF, yl, ylS, B, C, F, accf);
  };

  // ---- s2 conv (b=32) -> transition -> XH for block 1 ----
  k_dft1<<<1024, 64, 0, stream>>>(x, XS2, 64);
  k_analysis_s2<<<dim3(cdiv(16L*63, 256), 32), 256, 0, stream>>>(XS2, wigT[0], qwT[0], XHS, 16, 64);
  k_kh_s2<<<dim3(cdiv(64L*63, 256), 32), 256, 0, stream>>>(ks2, d0T[0], KHS, 4, 16);
  k_rank1<<<dim3(cdiv(64L*3969, 256), 32), 256, 0, stream>>>(XHS, KHS, YL, 4, 4, 16, 43680);
  transition(YL, 43680, 32, wigT[0], 64, wigT[0], qwT[0], 32, 43680, XH, 64);

  // ---- residual blocks ----
  const float* wa_[4] = {(const float*)d_in[2], (const float*)d_in[5], (const float*)d_in[8],  (const float*)d_in[11]};
  const float* wb_[4] = {(const float*)d_in[3], (const float*)d_in[6], (const float*)d_in[9],  (const float*)d_in[12]};
  const float* wsn[4] = {(const float*)d_in[4], (const float*)d_in[7], (const float*)d_in[10], (const float*)d_in[13]};
  const int Cs[4] = {16, 32, 64, 128}, Fs[4] = {32, 64, 128, 256};

  for (int blk = 0; blk < 4; ++blk) {
    const int bw = bl[blk], C = Cs[blk], F = Fs[blk], B = 4;
    const int L = bw, Lh = bw/2, K = 2*bw, Kh = bw;
    const int Sa = Sof(L), Sh = Sof(Lh);

    conv(wa_[blk], d0T[blk], XH, Sa, YL, Sa, B, C, C, L, 0);
    transition(YL, Sa, L, wigT[blk], K, wigT[blk], qwT[blk], Lh, Sh, XHA, B*C);
    conv(wb_[blk], d0T[blk], XHA, Sh, YL, Sh, B, C, F, Lh, 0);
    conv(wsn[blk], d0T[blk], XH, Sa, YL, Sh, B, C, F, Lh, 1);

    if (blk < 3) {
      transition(YL, Sh, Lh, wigT[blk+1], Kh, wigT[blk+1], qwT[blk+1], Lh, Sh, XH, B*F);
    } else {
      size_t lds = sizeof(float2)*((size_t)Kh/2 + (size_t)Kh*(Kh+1) + (size_t)Kh*Kh/2);
      k_trans<<<B*F*Kh, 256, lds, stream>>>(YL, Sh, wigT[4], Lh, nullptr, OUTS, Kh, 0);
    }
  }

  // ---- integrate (b=2) + linear head ----
  k_final<<<4, 256, 0, stream>>>(OUTS, qwT[4], lw, lb, out);
}